// Round 11
// baseline (83.719 us; speedup 1.0000x reference)
//
#include <hip/hip_runtime.h>

#define N_NODES 50000
#define F_IN    512
#define F_OUT   96
#define N_EDGES 800000

#define RPB    128                          // rows per coarse bucket
#define NBKT   391                          // ceil(50000/128)
#define CAP    2560                         // bucket capacity (mean 2048, +11 sigma)
#define ECHUNK 4096
#define NCHUNK ((N_EDGES + ECHUNK - 1) / ECHUNK)   // 196
#define GEMM_BLOCKS ((N_NODES + 63) / 64)          // 782

typedef __attribute__((ext_vector_type(8))) short bf16x8;
typedef __attribute__((ext_vector_type(4))) float f32x4;

typedef const __attribute__((address_space(1))) void* gas_ptr;
typedef __attribute__((address_space(3))) void* las_ptr;

__device__ __forceinline__ void gload_lds16(const void* g, void* l) {
    __builtin_amdgcn_global_load_lds((gas_ptr)g, (las_ptr)l, 16, 0, 0);
}

// f32 -> bf16 round-to-nearest-even (bit pattern)
__device__ __forceinline__ unsigned short f2bf(float f) {
    unsigned int u = __float_as_uint(f);
    unsigned int r = (u + 0x7FFFu + ((u >> 16) & 1u)) >> 16;
    return (unsigned short)r;
}
__device__ __forceinline__ float bf2f(unsigned short h) {
    return __uint_as_float(((unsigned int)h) << 16);
}

// ---------------------------------------------------------------------------
// Weight cast (+ fused bcnt-zero): w[512][96] f32 -> wTp[p][n][k'] bf16,
// panel-major, XOR-swizzled: slot = k' ^ ((n&7)<<3).
// ---------------------------------------------------------------------------
__global__ __launch_bounds__(256) void k_wcast(const float* __restrict__ w,
                                               unsigned short* __restrict__ wTp,
                                               int* __restrict__ bcnt) {
    if (blockIdx.x == 0) {
        const int t = threadIdx.x;
        bcnt[t] = 0;                       // 0..255
        if (t < 144) bcnt[256 + t] = 0;    // 256..399
    }
    const int i = blockIdx.x * 256 + threadIdx.x;
    if (i < F_OUT * F_IN) {
        const int n  = i >> 9;
        const int k  = i & 511;
        const int p  = k >> 6;
        const int kk = k & 63;
        const int slot = kk ^ ((n & 7) << 3);
        wTp[p * (F_OUT * 64) + n * 64 + slot] = f2bf(w[(size_t)k * F_OUT + n]);
    }
}

// ---------------------------------------------------------------------------
// FUSED: blocks [0, NCHUNK) = edge multisplit fill; rest = MFMA GEMM.
// GEMM v2: NO barriers in the K-pipeline. A loads go global->reg in MFMA
// fragment layout, 3 panels deep, fully unrolled (static indices -> regs);
// compiler emits counted waitcnts so loads stay in flight continuously.
// B staged in LDS in two 4-panel halves (48 KB); only 3 __syncthreads total.
// ---------------------------------------------------------------------------
__global__ __launch_bounds__(256) void k_fused(const float* __restrict__ x,
                                               const unsigned short* __restrict__ wTp,
                                               unsigned short* __restrict__ support,
                                               const int* __restrict__ erow,
                                               const int* __restrict__ ecol,
                                               const float* __restrict__ eval,
                                               int* __restrict__ bcnt,
                                               float2* __restrict__ bucket) {
    __shared__ __align__(16) char smem[49152];   // 48 KB
    const int tid = threadIdx.x;

    if (blockIdx.x < NCHUNK) {
        // ---------------- fill path ----------------
        int* hist  = (int*)smem;          // [NBKT]
        int* gbase = hist + 400;          // [NBKT]
        int* lcur  = gbase + 400;         // [NBKT]
        for (int i = tid; i < NBKT; i += 256) { hist[i] = 0; lcur[i] = 0; }
        __syncthreads();

        const int base = blockIdx.x * ECHUNK;
        const int n = min(ECHUNK, N_EDGES - base);

        for (int i = tid; i < n; i += 256)
            atomicAdd(&hist[erow[base + i] >> 7], 1);
        __syncthreads();

        for (int b = tid; b < NBKT; b += 256)
            gbase[b] = hist[b] ? atomicAdd(&bcnt[b], hist[b]) : 0;
        __syncthreads();

        for (int i = tid; i < n; i += 256) {
            const int r = erow[base + i];
            const int b = r >> 7;
            const int pos = gbase[b] + atomicAdd(&lcur[b], 1);
            if (pos >= 0 && pos < CAP)
                bucket[(size_t)b * CAP + pos] = make_float2(
                    __int_as_float(((r & 127) << 16) | ecol[base + i]),
                    eval[base + i]);
        }
        return;
    }

    // ---------------- GEMM path ----------------
    unsigned short* sB = (unsigned short*)smem;   // [4][64*96] bf16, swizzled

    const int lane = tid & 63;
    const int wave = tid >> 6;
    const int r0   = (blockIdx.x - NCHUNK) * 64;
    const int lr   = lane & 15;        // A-row (in wave tile) / B-col / C-col
    const int kg   = lane >> 4;        // k-group 0..3

    int grow = r0 + wave * 16 + lr;
    if (grow > N_NODES - 1) grow = N_NODES - 1;     // clamp: dup row, store-masked
    const float* xrow = x + (size_t)grow * F_IN + kg * 8;

    f32x4 acc[6];
    #pragma unroll
    for (int t = 0; t < 6; ++t) acc[t] = (f32x4){0.f, 0.f, 0.f, 0.f};

    float4 ar[8][4];   // per-panel A regs; all indices static after unroll

    auto BSTAGE = [&](int half) {
        const unsigned short* src = wTp + (size_t)half * (4 * F_OUT * 64);
        #pragma unroll
        for (int i = 0; i < 12; ++i) {
            const int chunk = i * 256 + tid;       // 0..3071 (16B chunks)
            gload_lds16(src + chunk * 8, sB + chunk * 8);
        }
    };
    auto XLOAD = [&](int p) {
        const float* b = xrow + p * 64;
        ar[p][0] = *reinterpret_cast<const float4*>(b);          // ks=0 lo
        ar[p][1] = *reinterpret_cast<const float4*>(b + 4);      // ks=0 hi
        ar[p][2] = *reinterpret_cast<const float4*>(b + 32);     // ks=1 lo
        ar[p][3] = *reinterpret_cast<const float4*>(b + 36);     // ks=1 hi
    };
    auto COMPUTE = [&](int p) {
        const char* bb = (const char*)(sB + (p & 3) * (F_OUT * 64));
        #pragma unroll
        for (int ks = 0; ks < 2; ++ks) {
            const float4 a0 = ar[p][ks * 2];
            const float4 a1 = ar[p][ks * 2 + 1];
            bf16x8 af;
            af[0] = (short)f2bf(a0.x); af[1] = (short)f2bf(a0.y);
            af[2] = (short)f2bf(a0.z); af[3] = (short)f2bf(a0.w);
            af[4] = (short)f2bf(a1.x); af[5] = (short)f2bf(a1.y);
            af[6] = (short)f2bf(a1.z); af[7] = (short)f2bf(a1.w);
            #pragma unroll
            for (int t = 0; t < 6; ++t) {
                const int n    = t * 16 + lr;
                const int boff = (ks * 64 + kg * 16) ^ ((n & 7) << 4);
                const bf16x8 bfr = *reinterpret_cast<const bf16x8*>(bb + n * 128 + boff);
                acc[t] = __builtin_amdgcn_mfma_f32_16x16x32_bf16(af, bfr, acc[t], 0, 0, 0);
            }
        }
    };

    BSTAGE(0);                     // panels 0-3 -> LDS
    __syncthreads();               // one-time drain; nothing else in flight
    XLOAD(0); XLOAD(1); XLOAD(2);  // 3-deep A prefetch, stays in flight
    COMPUTE(0); XLOAD(3);
    COMPUTE(1); XLOAD(4);          // A(4) independent of sB half flip
    COMPUTE(2); XLOAD(5);
    COMPUTE(3);
    __syncthreads();               // all waves done reading sB half 0
    BSTAGE(1);                     // panels 4-7 -> same LDS
    __syncthreads();               // drain B stage (A(4),A(5) also land; fine)
    XLOAD(6);
    COMPUTE(4); XLOAD(7);
    COMPUTE(5);
    COMPUTE(6);
    COMPUTE(7);

    // ---- store (bf16): C col = lr, row = kg*4 + reg ----
    #pragma unroll
    for (int t = 0; t < 6; ++t) {
        #pragma unroll
        for (int r = 0; r < 4; ++r) {
            const int row = r0 + wave * 16 + kg * 4 + r;
            if (row < N_NODES)
                support[(size_t)row * F_OUT + t * 16 + lr] = f2bf(acc[t][r]);
        }
    }
}

// ---------------------------------------------------------------------------
// S: in-bucket row sort -> bucket2 (fixed-cap layout) + per-row offsets.
// rowOffs layout: [b*129 + 0..127] = row bases, [b*129 + 128] = bucket end.
// ---------------------------------------------------------------------------
__global__ __launch_bounds__(256) void kS_sort(const int* __restrict__ bcnt,
                                               const float2* __restrict__ bucket,
                                               float2* __restrict__ bucket2,
                                               int* __restrict__ rowOffs) {
    __shared__ int cnt[RPB];
    __shared__ int sc[RPB];
    __shared__ int rbase[RPB];
    __shared__ int rcur[RPB];
    const int b   = blockIdx.x;
    const int tid = threadIdx.x;

    if (tid < RPB) { cnt[tid] = 0; rcur[tid] = 0; }
    __syncthreads();

    const int beg = b * CAP;
    const int n   = min(bcnt[b], CAP);

    for (int i = tid; i < n; i += 256)
        atomicAdd(&cnt[(__float_as_int(bucket[beg + i].x) >> 16) & 127], 1);
    __syncthreads();

    if (tid < RPB) sc[tid] = cnt[tid];
    __syncthreads();
    #pragma unroll
    for (int off = 1; off < RPB; off <<= 1) {
        int a = 0;
        if (tid < RPB && tid >= off) a = sc[tid - off];
        __syncthreads();
        if (tid < RPB) sc[tid] += a;
        __syncthreads();
    }
    if (tid < RPB) {
        const int rb = beg + sc[tid] - cnt[tid];   // exclusive
        rbase[tid] = rb;
        rowOffs[b * 129 + tid] = rb;
    }
    if (tid == RPB) rowOffs[b * 129 + RPB] = beg + n;
    __syncthreads();

    for (int i = tid; i < n; i += 256) {
        const float2 ev  = bucket[beg + i];
        const int    key = __float_as_int(ev.x);
        const int    r   = (key >> 16) & 127;
        const int    pos = rbase[r] + atomicAdd(&rcur[r], 1);
        bucket2[pos] = make_float2(__int_as_float(key & 0xFFFF), ev.y);
    }
}

// ---------------------------------------------------------------------------
// Gather: thread = (row, f16), f16 in [0,6) -> 16 features. bf16 support.
// Register accumulate, fused ReLU, single write. No atomics.
// ---------------------------------------------------------------------------
__global__ __launch_bounds__(256) void k_gather(const int* __restrict__ rowOffs,
                                                const float2* __restrict__ bucket2,
                                                const unsigned short* __restrict__ support,
                                                float* __restrict__ out) {
    const int gid = blockIdx.x * 256 + threadIdx.x;
    if (gid >= N_NODES * 6) return;
    const int r   = gid / 6;
    const int f16 = gid - r * 6;

    const int idx = (r >> 7) * 129 + (r & 127);
    const int beg = rowOffs[idx];
    const int end = rowOffs[idx + 1];

    float acc[16];
    #pragma unroll
    for (int j = 0; j < 16; ++j) acc[j] = 0.f;

    for (int i = beg; i < end; ++i) {
        const float2 cv = bucket2[i];
        const int   c = __float_as_int(cv.x);
        const float v = cv.y;
        const unsigned short* sp = support + (size_t)c * F_OUT + f16 * 16;
        const bf16x8 s0 = *reinterpret_cast<const bf16x8*>(sp);
        const bf16x8 s1 = *reinterpret_cast<const bf16x8*>(sp + 8);
        #pragma unroll
        for (int j = 0; j < 8; ++j) {
            acc[j]     = fmaf(v, bf2f((unsigned short)s0[j]), acc[j]);
            acc[8 + j] = fmaf(v, bf2f((unsigned short)s1[j]), acc[8 + j]);
        }
    }

    float* o = out + (size_t)r * F_OUT + f16 * 16;
    #pragma unroll
    for (int q = 0; q < 4; ++q) {
        float4 ov;
        ov.x = fmaxf(acc[q * 4 + 0], 0.f);
        ov.y = fmaxf(acc[q * 4 + 1], 0.f);
        ov.z = fmaxf(acc[q * 4 + 2], 0.f);
        ov.w = fmaxf(acc[q * 4 + 3], 0.f);
        *reinterpret_cast<float4*>(o + q * 4) = ov;
    }
}

extern "C" void kernel_launch(void* const* d_in, const int* in_sizes, int n_in,
                              void* d_out, int out_size, void* d_ws, size_t ws_size,
                              hipStream_t stream) {
    const float* x    = (const float*)d_in[0];
    const int*   erow = (const int*)d_in[1];
    const int*   ecol = (const int*)d_in[2];
    const float* eval = (const float*)d_in[3];
    const float* w    = (const float*)d_in[4];
    float*       out  = (float*)d_out;

    // workspace layout (bytes from d_ws):
    unsigned short* support = (unsigned short*)d_ws;               // 9.6 MB
    int*    bcnt    = (int*)((char*)d_ws + 9600000);               // [391] pad 400
    int*    rowOffs = bcnt + 400;                                  // [50439] pad 50560
    unsigned short* wTp = (unsigned short*)(rowOffs + 50560);      // 49152 bf16
    float2* bucket  = (float2*)((char*)wTp + 98304);               // 8.0 MB
    float2* bucket2 = bucket + (size_t)NBKT * CAP;                 // 8.0 MB

    k_wcast<<<(F_OUT * F_IN + 255) / 256, 256, 0, stream>>>(w, wTp, bcnt);

    k_fused<<<NCHUNK + GEMM_BLOCKS, 256, 0, stream>>>(x, wTp, support,
                                                      erow, ecol, eval,
                                                      bcnt, bucket);

    kS_sort<<<NBKT, 256, 0, stream>>>(bcnt, bucket, bucket2, rowOffs);

    const int gthreads = N_NODES * 6;
    k_gather<<<(gthreads + 255) / 256, 256, 0, stream>>>(rowOffs, bucket2, support, out);
}

// Round 12
// 82.332 us; speedup vs baseline: 1.0169x; 1.0169x over previous
//
#include <hip/hip_runtime.h>

#define N_NODES 50000
#define F_IN    512
#define F_OUT   96
#define N_EDGES 800000

#define RPB    128                          // rows per coarse bucket
#define NBKT   391                          // ceil(50000/128)
#define CAP    2560                         // bucket capacity (mean 2048, +11 sigma)
#define ECHUNK 4096
#define NCHUNK ((N_EDGES + ECHUNK - 1) / ECHUNK)   // 196
#define GEMM_BLOCKS ((N_NODES + 63) / 64)          // 782

typedef __attribute__((ext_vector_type(8))) short bf16x8;
typedef __attribute__((ext_vector_type(4))) float f32x4;

typedef const __attribute__((address_space(1))) void* gas_ptr;
typedef __attribute__((address_space(3))) void* las_ptr;

__device__ __forceinline__ void gload_lds16(const void* g, void* l) {
    __builtin_amdgcn_global_load_lds((gas_ptr)g, (las_ptr)l, 16, 0, 0);
}

// asm-pinned global load: compiler cannot sink/elide it (volatile), and the
// "memory" clobber keeps all other memory ops (incl. gload_lds) ordered, so
// static vmcnt counting below stays exact.
__device__ __forceinline__ float4 gload4(const float* p) {
    float4 r;
    asm volatile("global_load_dwordx4 %0, %1, off"
                 : "=v"(r) : "v"(p) : "memory");
    return r;
}

// counted wait + scheduler fence (rule #18: sched_barrier after asm waitcnt)
#define VMCNT_SB(n) do { \
    asm volatile("s_waitcnt vmcnt(" #n ")" ::: "memory"); \
    __builtin_amdgcn_sched_barrier(0); \
} while (0)

// f32 -> bf16 round-to-nearest-even (bit pattern)
__device__ __forceinline__ unsigned short f2bf(float f) {
    unsigned int u = __float_as_uint(f);
    unsigned int r = (u + 0x7FFFu + ((u >> 16) & 1u)) >> 16;
    return (unsigned short)r;
}
__device__ __forceinline__ float bf2f(unsigned short h) {
    return __uint_as_float(((unsigned int)h) << 16);
}

// ---------------------------------------------------------------------------
// Weight cast (+ fused bcnt-zero): w[512][96] f32 -> wTp[p][n][k'] bf16,
// panel-major, XOR-swizzled: slot = k' ^ ((n&7)<<3).
// ---------------------------------------------------------------------------
__global__ __launch_bounds__(256) void k_wcast(const float* __restrict__ w,
                                               unsigned short* __restrict__ wTp,
                                               int* __restrict__ bcnt) {
    if (blockIdx.x == 0) {
        const int t = threadIdx.x;
        bcnt[t] = 0;                       // 0..255
        if (t < 144) bcnt[256 + t] = 0;    // 256..399
    }
    const int i = blockIdx.x * 256 + threadIdx.x;
    if (i < F_OUT * F_IN) {
        const int n  = i >> 9;
        const int k  = i & 511;
        const int p  = k >> 6;
        const int kk = k & 63;
        const int slot = kk ^ ((n & 7) << 3);
        wTp[p * (F_OUT * 64) + n * 64 + slot] = f2bf(w[(size_t)k * F_OUT + n]);
    }
}

// ---------------------------------------------------------------------------
// FUSED: blocks [0, NCHUNK) = edge multisplit fill; rest = MFMA GEMM.
// GEMM v3 (T4): x loads are asm-pinned global->reg, pipelined 4 panels deep
// with STATIC vmcnt counting; B staged via gload_lds into two 24 KB ping-pong
// regions (2 panels each); 4 raw s_barriers total, never vmcnt(0) mid-loop.
// Per-wave issue/wait ledger (out = outstanding VMEM instrs):
//   B(R0)6 B(R1)6 x0..x3(16)=28 | VMCNT16 bar | p0:V12,c,x4 | p1:V12,c,x5
//   bar B(R0)6 | p2:V18,c,x6 | p3:V18,c,x7 | V8 bar B(R1)6 | p4:c | p5:c
//   | V0 bar | p6:c p7:c
// ---------------------------------------------------------------------------
__global__ __launch_bounds__(256) void k_fused(const float* __restrict__ x,
                                               const unsigned short* __restrict__ wTp,
                                               unsigned short* __restrict__ support,
                                               const int* __restrict__ erow,
                                               const int* __restrict__ ecol,
                                               const float* __restrict__ eval,
                                               int* __restrict__ bcnt,
                                               float2* __restrict__ bucket) {
    __shared__ __align__(16) char smem[49152];   // 48 KB (GEMM: 2x24KB B regions)
    const int tid = threadIdx.x;

    if (blockIdx.x < NCHUNK) {
        // ---------------- fill path ----------------
        int* hist  = (int*)smem;          // [NBKT]
        int* gbase = hist + 400;          // [NBKT]
        int* lcur  = gbase + 400;         // [NBKT]
        for (int i = tid; i < NBKT; i += 256) { hist[i] = 0; lcur[i] = 0; }
        __syncthreads();

        const int base = blockIdx.x * ECHUNK;
        const int n = min(ECHUNK, N_EDGES - base);

        for (int i = tid; i < n; i += 256)
            atomicAdd(&hist[erow[base + i] >> 7], 1);
        __syncthreads();

        for (int b = tid; b < NBKT; b += 256)
            gbase[b] = hist[b] ? atomicAdd(&bcnt[b], hist[b]) : 0;
        __syncthreads();

        for (int i = tid; i < n; i += 256) {
            const int r = erow[base + i];
            const int b = r >> 7;
            const int pos = gbase[b] + atomicAdd(&lcur[b], 1);
            if (pos >= 0 && pos < CAP)
                bucket[(size_t)b * CAP + pos] = make_float2(
                    __int_as_float(((r & 127) << 16) | ecol[base + i]),
                    eval[base + i]);
        }
        return;
    }

    // ---------------- GEMM path ----------------
    const int lane = tid & 63;
    const int wave = tid >> 6;
    const int r0   = (blockIdx.x - NCHUNK) * 64;
    const int lr   = lane & 15;        // A-row (in wave tile) / B-col / C-col
    const int kg   = lane >> 4;        // k-group 0..3

    int grow = r0 + wave * 16 + lr;
    if (grow > N_NODES - 1) grow = N_NODES - 1;     // clamp: dup row, store-masked
    const float* xrow = x + (size_t)grow * F_IN + kg * 8;

    f32x4 acc[6];
    #pragma unroll
    for (int t = 0; t < 6; ++t) acc[t] = (f32x4){0.f, 0.f, 0.f, 0.f};

    // B staging: one pair of panels (24 KB) into region r
    auto BSTAGE = [&](int reg, int pair) {
        const unsigned short* src = wTp + (size_t)pair * (2 * F_OUT * 64);
        char* dst = smem + reg * 24576;
        #pragma unroll
        for (int i = 0; i < 6; ++i) {
            const int chunk = i * 256 + tid;       // 0..1535 (16B chunks)
            gload_lds16(src + chunk * 8, dst + chunk * 16);
        }
    };

    float4 ar[8][4];   // straight-line code below -> all indices static

    auto XLOAD = [&](int p) {
        const float* b = xrow + p * 64;
        ar[p][0] = gload4(b);
        ar[p][1] = gload4(b + 4);
        ar[p][2] = gload4(b + 32);
        ar[p][3] = gload4(b + 36);
    };
    auto COMPUTE = [&](int p) {
        const char* bb = smem + (((p >> 1) & 1) * 24576) + ((p & 1) * 12288);
        #pragma unroll
        for (int ks = 0; ks < 2; ++ks) {
            const float4 a0 = ar[p][ks * 2];
            const float4 a1 = ar[p][ks * 2 + 1];
            bf16x8 af;
            af[0] = (short)f2bf(a0.x); af[1] = (short)f2bf(a0.y);
            af[2] = (short)f2bf(a0.z); af[3] = (short)f2bf(a0.w);
            af[4] = (short)f2bf(a1.x); af[5] = (short)f2bf(a1.y);
            af[6] = (short)f2bf(a1.z); af[7] = (short)f2bf(a1.w);
            #pragma unroll
            for (int t = 0; t < 6; ++t) {
                const int n    = t * 16 + lr;
                const int boff = (ks * 64 + kg * 16) ^ ((n & 7) << 4);
                const bf16x8 bfr = *reinterpret_cast<const bf16x8*>(bb + n * 128 + boff);
                acc[t] = __builtin_amdgcn_mfma_f32_16x16x32_bf16(af, bfr, acc[t], 0, 0, 0);
            }
        }
    };

    BSTAGE(0, 0);                  // panels 0,1 -> R0      out=6
    BSTAGE(1, 1);                  // panels 2,3 -> R1      out=12
    XLOAD(0); XLOAD(1); XLOAD(2); XLOAD(3);             // out=28
    VMCNT_SB(16);                  // B pairs 0,1 drained; x0..x3 in flight
    __builtin_amdgcn_s_barrier();  // bar1: sB R0+R1 visible to all waves

    VMCNT_SB(12); COMPUTE(0); XLOAD(4);                 // out=16
    VMCNT_SB(12); COMPUTE(1); XLOAD(5);                 // out=16
    __builtin_amdgcn_s_barrier();  // bar2: all waves done reading R0
    BSTAGE(0, 2);                  // panels 4,5 -> R0      out=22
    VMCNT_SB(18); COMPUTE(2); XLOAD(6);                 // out=22
    VMCNT_SB(18); COMPUTE(3); XLOAD(7);                 // out=22
    VMCNT_SB(8);                   // drains x4,x5,B45; x6,x7 in flight
    __builtin_amdgcn_s_barrier();  // bar3: B45 complete cross-wave; R1 free
    BSTAGE(1, 3);                  // panels 6,7 -> R1      out=14
    COMPUTE(4);
    COMPUTE(5);
    VMCNT_SB(0);                   // drain x6,x7,B67
    __builtin_amdgcn_s_barrier();  // bar4: B67 complete cross-wave
    COMPUTE(6);
    COMPUTE(7);

    // ---- store (bf16): C col = lr, row = kg*4 + reg ----
    #pragma unroll
    for (int t = 0; t < 6; ++t) {
        #pragma unroll
        for (int r = 0; r < 4; ++r) {
            const int row = r0 + wave * 16 + kg * 4 + r;
            if (row < N_NODES)
                support[(size_t)row * F_OUT + t * 16 + lr] = f2bf(acc[t][r]);
        }
    }
}

// ---------------------------------------------------------------------------
// S: in-bucket row sort -> bucket2 (fixed-cap layout) + per-row offsets.
// rowOffs layout: [b*129 + 0..127] = row bases, [b*129 + 128] = bucket end.
// ---------------------------------------------------------------------------
__global__ __launch_bounds__(256) void kS_sort(const int* __restrict__ bcnt,
                                               const float2* __restrict__ bucket,
                                               float2* __restrict__ bucket2,
                                               int* __restrict__ rowOffs) {
    __shared__ int cnt[RPB];
    __shared__ int sc[RPB];
    __shared__ int rbase[RPB];
    __shared__ int rcur[RPB];
    const int b   = blockIdx.x;
    const int tid = threadIdx.x;

    if (tid < RPB) { cnt[tid] = 0; rcur[tid] = 0; }
    __syncthreads();

    const int beg = b * CAP;
    const int n   = min(bcnt[b], CAP);

    for (int i = tid; i < n; i += 256)
        atomicAdd(&cnt[(__float_as_int(bucket[beg + i].x) >> 16) & 127], 1);
    __syncthreads();

    if (tid < RPB) sc[tid] = cnt[tid];
    __syncthreads();
    #pragma unroll
    for (int off = 1; off < RPB; off <<= 1) {
        int a = 0;
        if (tid < RPB && tid >= off) a = sc[tid - off];
        __syncthreads();
        if (tid < RPB) sc[tid] += a;
        __syncthreads();
    }
    if (tid < RPB) {
        const int rb = beg + sc[tid] - cnt[tid];   // exclusive
        rbase[tid] = rb;
        rowOffs[b * 129 + tid] = rb;
    }
    if (tid == RPB) rowOffs[b * 129 + RPB] = beg + n;
    __syncthreads();

    for (int i = tid; i < n; i += 256) {
        const float2 ev  = bucket[beg + i];
        const int    key = __float_as_int(ev.x);
        const int    r   = (key >> 16) & 127;
        const int    pos = rbase[r] + atomicAdd(&rcur[r], 1);
        bucket2[pos] = make_float2(__int_as_float(key & 0xFFFF), ev.y);
    }
}

// ---------------------------------------------------------------------------
// Gather: thread = (row, f16), f16 in [0,6) -> 16 features. bf16 support.
// Register accumulate, fused ReLU, single write. No atomics.
// ---------------------------------------------------------------------------
__global__ __launch_bounds__(256) void k_gather(const int* __restrict__ rowOffs,
                                                const float2* __restrict__ bucket2,
                                                const unsigned short* __restrict__ support,
                                                float* __restrict__ out) {
    const int gid = blockIdx.x * 256 + threadIdx.x;
    if (gid >= N_NODES * 6) return;
    const int r   = gid / 6;
    const int f16 = gid - r * 6;

    const int idx = (r >> 7) * 129 + (r & 127);
    const int beg = rowOffs[idx];
    const int end = rowOffs[idx + 1];

    float acc[16];
    #pragma unroll
    for (int j = 0; j < 16; ++j) acc[j] = 0.f;

    for (int i = beg; i < end; ++i) {
        const float2 cv = bucket2[i];
        const int   c = __float_as_int(cv.x);
        const float v = cv.y;
        const unsigned short* sp = support + (size_t)c * F_OUT + f16 * 16;
        const bf16x8 s0 = *reinterpret_cast<const bf16x8*>(sp);
        const bf16x8 s1 = *reinterpret_cast<const bf16x8*>(sp + 8);
        #pragma unroll
        for (int j = 0; j < 8; ++j) {
            acc[j]     = fmaf(v, bf2f((unsigned short)s0[j]), acc[j]);
            acc[8 + j] = fmaf(v, bf2f((unsigned short)s1[j]), acc[8 + j]);
        }
    }

    float* o = out + (size_t)r * F_OUT + f16 * 16;
    #pragma unroll
    for (int q = 0; q < 4; ++q) {
        float4 ov;
        ov.x = fmaxf(acc[q * 4 + 0], 0.f);
        ov.y = fmaxf(acc[q * 4 + 1], 0.f);
        ov.z = fmaxf(acc[q * 4 + 2], 0.f);
        ov.w = fmaxf(acc[q * 4 + 3], 0.f);
        *reinterpret_cast<float4*>(o + q * 4) = ov;
    }
}

extern "C" void kernel_launch(void* const* d_in, const int* in_sizes, int n_in,
                              void* d_out, int out_size, void* d_ws, size_t ws_size,
                              hipStream_t stream) {
    const float* x    = (const float*)d_in[0];
    const int*   erow = (const int*)d_in[1];
    const int*   ecol = (const int*)d_in[2];
    const float* eval = (const float*)d_in[3];
    const float* w    = (const float*)d_in[4];
    float*       out  = (float*)d_out;

    // workspace layout (bytes from d_ws):
    unsigned short* support = (unsigned short*)d_ws;               // 9.6 MB
    int*    bcnt    = (int*)((char*)d_ws + 9600000);               // [391] pad 400
    int*    rowOffs = bcnt + 400;                                  // [50439] pad 50560
    unsigned short* wTp = (unsigned short*)(rowOffs + 50560);      // 49152 bf16
    float2* bucket  = (float2*)((char*)wTp + 98304);               // 8.0 MB
    float2* bucket2 = bucket + (size_t)NBKT * CAP;                 // 8.0 MB

    k_wcast<<<(F_OUT * F_IN + 255) / 256, 256, 0, stream>>>(w, wTp, bcnt);

    k_fused<<<NCHUNK + GEMM_BLOCKS, 256, 0, stream>>>(x, wTp, support,
                                                      erow, ecol, eval,
                                                      bcnt, bucket);

    kS_sort<<<NBKT, 256, 0, stream>>>(bcnt, bucket, bucket2, rowOffs);

    const int gthreads = N_NODES * 6;
    k_gather<<<(gthreads + 255) / 256, 256, 0, stream>>>(rowOffs, bucket2, support, out);
}

// Round 13
// 81.146 us; speedup vs baseline: 1.0317x; 1.0146x over previous
//
#include <hip/hip_runtime.h>

#define N_NODES 50000
#define F_IN    512
#define F_OUT   96
#define N_EDGES 800000

#define RPB    128                          // rows per coarse bucket
#define NBKT   391                          // ceil(50000/128)
#define CAP    2560                         // bucket capacity (mean 2048, +11 sigma)
#define ECHUNK 4096
#define NCHUNK ((N_EDGES + ECHUNK - 1) / ECHUNK)   // 196
#define GEMM_BLOCKS ((N_NODES + 63) / 64)          // 782

typedef __attribute__((ext_vector_type(8))) short bf16x8;
typedef __attribute__((ext_vector_type(4))) float f32x4;

typedef const __attribute__((address_space(1))) void* gas_ptr;
typedef __attribute__((address_space(3))) void* las_ptr;

__device__ __forceinline__ void gload_lds16(const void* g, void* l) {
    __builtin_amdgcn_global_load_lds((gas_ptr)g, (las_ptr)l, 16, 0, 0);
}

// asm-pinned global load: cannot be sunk/elided; "memory" clobber keeps all
// VMEM (incl. gload_lds) in program order so static vmcnt counting is exact.
__device__ __forceinline__ float4 gload4(const float* p) {
    float4 r;
    asm volatile("global_load_dwordx4 %0, %1, off"
                 : "=v"(r) : "v"(p) : "memory");
    return r;
}

// counted wait + scheduler fence (rule #18)
#define VMCNT_SB(n) do { \
    asm volatile("s_waitcnt vmcnt(" #n ")" ::: "memory"); \
    __builtin_amdgcn_sched_barrier(0); \
} while (0)

// f32 -> bf16 round-to-nearest-even (bit pattern)
__device__ __forceinline__ unsigned short f2bf(float f) {
    unsigned int u = __float_as_uint(f);
    unsigned int r = (u + 0x7FFFu + ((u >> 16) & 1u)) >> 16;
    return (unsigned short)r;
}
__device__ __forceinline__ float bf2f(unsigned short h) {
    return __uint_as_float(((unsigned int)h) << 16);
}

// ---------------------------------------------------------------------------
// Weight cast (+ fused bcnt-zero): w[512][96] f32 -> wTp[p][n][k'] bf16,
// panel-major, XOR-swizzled: slot = k' ^ ((n&7)<<3).
// ---------------------------------------------------------------------------
__global__ __launch_bounds__(256) void k_wcast(const float* __restrict__ w,
                                               unsigned short* __restrict__ wTp,
                                               int* __restrict__ bcnt) {
    if (blockIdx.x == 0) {
        const int t = threadIdx.x;
        bcnt[t] = 0;                       // 0..255
        if (t < 144) bcnt[256 + t] = 0;    // 256..399
    }
    const int i = blockIdx.x * 256 + threadIdx.x;
    if (i < F_OUT * F_IN) {
        const int n  = i >> 9;
        const int k  = i & 511;
        const int p  = k >> 6;
        const int kk = k & 63;
        const int slot = kk ^ ((n & 7) << 3);
        wTp[p * (F_OUT * 64) + n * 64 + slot] = f2bf(w[(size_t)k * F_OUT + n]);
    }
}

// ---------------------------------------------------------------------------
// FUSED: blocks [0, NCHUNK) = edge multisplit fill; rest = MFMA GEMM.
// GEMM v4 = v3 ledger + __launch_bounds__(256,4): VGPR cap 128 so the 3-4
// panel A-register pipeline actually stays in registers (R12 spilled at 68).
// Ledger (out = outstanding VMEM per wave):
//  B0(6) B1(6) X0 X1 X2 (out 24) | vm12 bar1
//  vm8 C0 X3 (12) | vm8 C1 X4 (12) | bar2 B2(6) (18)
//  vm14 C2 X5 (18) | vm14 C3 X6 (18) | vm8 bar3 B3(6) (14)
//  C4 X7 (18) | vm14 C5 (14) | vm4 bar4 C6 (4) | vm0 C7
// ---------------------------------------------------------------------------
__global__ __launch_bounds__(256, 4) void k_fused(const float* __restrict__ x,
                                               const unsigned short* __restrict__ wTp,
                                               unsigned short* __restrict__ support,
                                               const int* __restrict__ erow,
                                               const int* __restrict__ ecol,
                                               const float* __restrict__ eval,
                                               int* __restrict__ bcnt,
                                               float2* __restrict__ bucket) {
    __shared__ __align__(16) char smem[49152];   // 48 KB (GEMM: 2x24KB B regions)
    const int tid = threadIdx.x;

    if (blockIdx.x < NCHUNK) {
        // ---------------- fill path ----------------
        int* hist  = (int*)smem;          // [NBKT]
        int* gbase = hist + 400;          // [NBKT]
        int* lcur  = gbase + 400;         // [NBKT]
        for (int i = tid; i < NBKT; i += 256) { hist[i] = 0; lcur[i] = 0; }
        __syncthreads();

        const int base = blockIdx.x * ECHUNK;
        const int n = min(ECHUNK, N_EDGES - base);

        for (int i = tid; i < n; i += 256)
            atomicAdd(&hist[erow[base + i] >> 7], 1);
        __syncthreads();

        for (int b = tid; b < NBKT; b += 256)
            gbase[b] = hist[b] ? atomicAdd(&bcnt[b], hist[b]) : 0;
        __syncthreads();

        for (int i = tid; i < n; i += 256) {
            const int r = erow[base + i];
            const int b = r >> 7;
            const int pos = gbase[b] + atomicAdd(&lcur[b], 1);
            if (pos >= 0 && pos < CAP)
                bucket[(size_t)b * CAP + pos] = make_float2(
                    __int_as_float(((r & 127) << 16) | ecol[base + i]),
                    eval[base + i]);
        }
        return;
    }

    // ---------------- GEMM path ----------------
    const int lane = tid & 63;
    const int wave = tid >> 6;
    const int r0   = (blockIdx.x - NCHUNK) * 64;
    const int lr   = lane & 15;        // A-row (in wave tile) / B-col / C-col
    const int kg   = lane >> 4;        // k-group 0..3

    int grow = r0 + wave * 16 + lr;
    if (grow > N_NODES - 1) grow = N_NODES - 1;     // clamp: dup row, store-masked
    const float* xrow = x + (size_t)grow * F_IN + kg * 8;

    f32x4 acc[6];
    #pragma unroll
    for (int t = 0; t < 6; ++t) acc[t] = (f32x4){0.f, 0.f, 0.f, 0.f};

    // B staging: one pair of panels (24 KB) into region reg
    auto BSTAGE = [&](int reg, int pair) {
        const unsigned short* src = wTp + (size_t)pair * (2 * F_OUT * 64);
        char* dst = smem + reg * 24576;
        #pragma unroll
        for (int i = 0; i < 6; ++i) {
            const int chunk = i * 256 + tid;       // 0..1535 (16B chunks)
            gload_lds16(src + chunk * 8, dst + chunk * 16);
        }
    };

    float4 ar[8][4];   // straight-line literal indices only -> registers

    auto XLOAD = [&](int p) {
        const float* b = xrow + p * 64;
        ar[p][0] = gload4(b);
        ar[p][1] = gload4(b + 4);
        ar[p][2] = gload4(b + 32);
        ar[p][3] = gload4(b + 36);
    };
    auto COMPUTE = [&](int p) {
        const char* bb = smem + (((p >> 1) & 1) * 24576) + ((p & 1) * 12288);
        #pragma unroll
        for (int ks = 0; ks < 2; ++ks) {
            const float4 a0 = ar[p][ks * 2];
            const float4 a1 = ar[p][ks * 2 + 1];
            bf16x8 af;
            af[0] = (short)f2bf(a0.x); af[1] = (short)f2bf(a0.y);
            af[2] = (short)f2bf(a0.z); af[3] = (short)f2bf(a0.w);
            af[4] = (short)f2bf(a1.x); af[5] = (short)f2bf(a1.y);
            af[6] = (short)f2bf(a1.z); af[7] = (short)f2bf(a1.w);
            #pragma unroll
            for (int t = 0; t < 6; ++t) {
                const int n    = t * 16 + lr;
                const int boff = (ks * 64 + kg * 16) ^ ((n & 7) << 4);
                const bf16x8 bfr = *reinterpret_cast<const bf16x8*>(bb + n * 128 + boff);
                acc[t] = __builtin_amdgcn_mfma_f32_16x16x32_bf16(af, bfr, acc[t], 0, 0, 0);
            }
        }
    };

    BSTAGE(0, 0);                   // panels 0,1 -> R0     out=6
    BSTAGE(1, 1);                   // panels 2,3 -> R1     out=12
    XLOAD(0); XLOAD(1); XLOAD(2);   //                      out=24
    VMCNT_SB(12);                   // B0,B1 drained; x0..x2 in flight
    __builtin_amdgcn_s_barrier();   // bar1: R0+R1 visible to all waves

    VMCNT_SB(8);  COMPUTE(0); XLOAD(3);   // out=12 (x1,x2,x3)
    VMCNT_SB(8);  COMPUTE(1); XLOAD(4);   // out=12 (x2,x3,x4)
    __builtin_amdgcn_s_barrier();   // bar2: all waves done reading R0
    BSTAGE(0, 2);                   // panels 4,5 -> R0     out=18
    VMCNT_SB(14); COMPUTE(2); XLOAD(5);   // out=18 (x3,x4,B2,x5)
    VMCNT_SB(14); COMPUTE(3); XLOAD(6);   // out=18 (x4,B2,x5,x6)
    VMCNT_SB(8);                    // drains x4,B2; x5,x6 in flight
    __builtin_amdgcn_s_barrier();   // bar3: R1 free + new R0 visible
    BSTAGE(1, 3);                   // panels 6,7 -> R1     out=14
    COMPUTE(4); XLOAD(7);           // x4 already retired   out=18
    VMCNT_SB(14); COMPUTE(5);       // x5 done              out=14
    VMCNT_SB(4);                    // drains x6,B3; x7 in flight
    __builtin_amdgcn_s_barrier();   // bar4: new R1 visible cross-wave
    COMPUTE(6);
    VMCNT_SB(0);                    // x7
    COMPUTE(7);

    // ---- store (bf16): C col = lr, row = kg*4 + reg ----
    #pragma unroll
    for (int t = 0; t < 6; ++t) {
        #pragma unroll
        for (int r = 0; r < 4; ++r) {
            const int row = r0 + wave * 16 + kg * 4 + r;
            if (row < N_NODES)
                support[(size_t)row * F_OUT + t * 16 + lr] = f2bf(acc[t][r]);
        }
    }
}

// ---------------------------------------------------------------------------
// S: in-bucket row sort -> bucket2 (fixed-cap layout) + per-row offsets.
// rowOffs layout: [b*129 + 0..127] = row bases, [b*129 + 128] = bucket end.
// ---------------------------------------------------------------------------
__global__ __launch_bounds__(256) void kS_sort(const int* __restrict__ bcnt,
                                               const float2* __restrict__ bucket,
                                               float2* __restrict__ bucket2,
                                               int* __restrict__ rowOffs) {
    __shared__ int cnt[RPB];
    __shared__ int sc[RPB];
    __shared__ int rbase[RPB];
    __shared__ int rcur[RPB];
    const int b   = blockIdx.x;
    const int tid = threadIdx.x;

    if (tid < RPB) { cnt[tid] = 0; rcur[tid] = 0; }
    __syncthreads();

    const int beg = b * CAP;
    const int n   = min(bcnt[b], CAP);

    for (int i = tid; i < n; i += 256)
        atomicAdd(&cnt[(__float_as_int(bucket[beg + i].x) >> 16) & 127], 1);
    __syncthreads();

    if (tid < RPB) sc[tid] = cnt[tid];
    __syncthreads();
    #pragma unroll
    for (int off = 1; off < RPB; off <<= 1) {
        int a = 0;
        if (tid < RPB && tid >= off) a = sc[tid - off];
        __syncthreads();
        if (tid < RPB) sc[tid] += a;
        __syncthreads();
    }
    if (tid < RPB) {
        const int rb = beg + sc[tid] - cnt[tid];   // exclusive
        rbase[tid] = rb;
        rowOffs[b * 129 + tid] = rb;
    }
    if (tid == RPB) rowOffs[b * 129 + RPB] = beg + n;
    __syncthreads();

    for (int i = tid; i < n; i += 256) {
        const float2 ev  = bucket[beg + i];
        const int    key = __float_as_int(ev.x);
        const int    r   = (key >> 16) & 127;
        const int    pos = rbase[r] + atomicAdd(&rcur[r], 1);
        bucket2[pos] = make_float2(__int_as_float(key & 0xFFFF), ev.y);
    }
}

// ---------------------------------------------------------------------------
// Gather: thread = (row, f16), f16 in [0,6) -> 16 features. bf16 support.
// Register accumulate, fused ReLU, single write. No atomics.
// ---------------------------------------------------------------------------
__global__ __launch_bounds__(256) void k_gather(const int* __restrict__ rowOffs,
                                                const float2* __restrict__ bucket2,
                                                const unsigned short* __restrict__ support,
                                                float* __restrict__ out) {
    const int gid = blockIdx.x * 256 + threadIdx.x;
    if (gid >= N_NODES * 6) return;
    const int r   = gid / 6;
    const int f16 = gid - r * 6;

    const int idx = (r >> 7) * 129 + (r & 127);
    const int beg = rowOffs[idx];
    const int end = rowOffs[idx + 1];

    float acc[16];
    #pragma unroll
    for (int j = 0; j < 16; ++j) acc[j] = 0.f;

    for (int i = beg; i < end; ++i) {
        const float2 cv = bucket2[i];
        const int   c = __float_as_int(cv.x);
        const float v = cv.y;
        const unsigned short* sp = support + (size_t)c * F_OUT + f16 * 16;
        const bf16x8 s0 = *reinterpret_cast<const bf16x8*>(sp);
        const bf16x8 s1 = *reinterpret_cast<const bf16x8*>(sp + 8);
        #pragma unroll
        for (int j = 0; j < 8; ++j) {
            acc[j]     = fmaf(v, bf2f((unsigned short)s0[j]), acc[j]);
            acc[8 + j] = fmaf(v, bf2f((unsigned short)s1[j]), acc[8 + j]);
        }
    }

    float* o = out + (size_t)r * F_OUT + f16 * 16;
    #pragma unroll
    for (int q = 0; q < 4; ++q) {
        float4 ov;
        ov.x = fmaxf(acc[q * 4 + 0], 0.f);
        ov.y = fmaxf(acc[q * 4 + 1], 0.f);
        ov.z = fmaxf(acc[q * 4 + 2], 0.f);
        ov.w = fmaxf(acc[q * 4 + 3], 0.f);
        *reinterpret_cast<float4*>(o + q * 4) = ov;
    }
}

extern "C" void kernel_launch(void* const* d_in, const int* in_sizes, int n_in,
                              void* d_out, int out_size, void* d_ws, size_t ws_size,
                              hipStream_t stream) {
    const float* x    = (const float*)d_in[0];
    const int*   erow = (const int*)d_in[1];
    const int*   ecol = (const int*)d_in[2];
    const float* eval = (const float*)d_in[3];
    const float* w    = (const float*)d_in[4];
    float*       out  = (float*)d_out;

    // workspace layout (bytes from d_ws):
    unsigned short* support = (unsigned short*)d_ws;               // 9.6 MB
    int*    bcnt    = (int*)((char*)d_ws + 9600000);               // [391] pad 400
    int*    rowOffs = bcnt + 400;                                  // [50439] pad 50560
    unsigned short* wTp = (unsigned short*)(rowOffs + 50560);      // 49152 bf16
    float2* bucket  = (float2*)((char*)wTp + 98304);               // 8.0 MB
    float2* bucket2 = bucket + (size_t)NBKT * CAP;                 // 8.0 MB

    k_wcast<<<(F_OUT * F_IN + 255) / 256, 256, 0, stream>>>(w, wTp, bcnt);

    k_fused<<<NCHUNK + GEMM_BLOCKS, 256, 0, stream>>>(x, wTp, support,
                                                      erow, ecol, eval,
                                                      bcnt, bucket);

    kS_sort<<<NBKT, 256, 0, stream>>>(bcnt, bucket, bucket2, rowOffs);

    const int gthreads = N_NODES * 6;
    k_gather<<<(gthreads + 255) / 256, 256, 0, stream>>>(rowOffs, bucket2, support, out);
}